// Round 19
// baseline (83.521 us; speedup 1.0000x reference)
//
#include <hip/hip_runtime.h>

// MHA: B=4 T=1024 E=1024 H=16 D=64, causal, f32 in/out, bf16 internal compute.
// cast -> GEMM1 (Q/K plain [B,H,T,D], V direct-transposed [B,H,D,T]) -> flash attn
// -> GEMM2 (+bias)
// R19: GEMM1 BN 128->64 (grid (32,48)=1536 blocks, 48KB LDS -> 3 blocks/CU, clean
//      6x256 tail). In-session evidence: GEMM2 at BN=64 runs ~860 TF vs GEMM1's 713
//      at identical loop body — co-residency covers the drain stall. Rest frozen (R18).

#define T_SZ 1024
#define E_SZ 1024
#define H_SZ 16
#define D_SZ 64

typedef __attribute__((ext_vector_type(8))) short bf16x8;
typedef __attribute__((ext_vector_type(4))) short bf16x4;
typedef __attribute__((ext_vector_type(4))) float f32x4;

static __device__ __forceinline__ unsigned short f2b(float f) {
  unsigned int u = __builtin_bit_cast(unsigned int, f);
  u += 0x7fffu + ((u >> 16) & 1u);   // RNE
  return (unsigned short)(u >> 16);
}

static __device__ __forceinline__ unsigned int cvt_pk(float lo, float hi) {
  unsigned int r;
  asm("v_cvt_pk_bf16_f32 %0, %1, %2" : "=v"(r) : "v"(lo), "v"(hi));
  return r;
}

static __device__ __forceinline__ void load_lds16(const void* g, void* l) {
  __builtin_amdgcn_global_load_lds(
      (const __attribute__((address_space(1))) void*)g,
      (__attribute__((address_space(3))) void*)l, 16, 0, 0);
}

// ---------------- fused cast f32 -> bf16 ----------------
__global__ void cast_all(const float* __restrict__ x, const float* __restrict__ wq,
                         const float* __restrict__ wk, const float* __restrict__ wv,
                         const float* __restrict__ wp,
                         unsigned short* __restrict__ xb,
                         unsigned short* __restrict__ wqkvb,
                         unsigned short* __restrict__ wpb) {
  int b = blockIdx.x;
  const float4* src;
  ushort4* dst;
  int i;
  if (b < 4096) {
    src = (const float4*)x; dst = (ushort4*)xb; i = b * 256 + threadIdx.x;
  } else {
    int a = (b - 4096) >> 10;
    i = ((b - 4096) & 1023) * 256 + threadIdx.x;
    src = (const float4*)(a == 0 ? wq : a == 1 ? wk : a == 2 ? wv : wp);
    dst = (ushort4*)(a == 3 ? wpb : wqkvb + (size_t)a * 1048576);
  }
  float4 v = src[i];
  ushort4 o;
  o.x = f2b(v.x); o.y = f2b(v.y); o.z = f2b(v.z); o.w = f2b(v.w);
  dst[i] = o;
}

// ---------------- GEMM C[M,N] = A[M,K] * B[N,K]^T (R15-proven) ----------------
template <int EPI, int BN>
__global__ void gemm_bt(const unsigned short* __restrict__ A,
                        const unsigned short* __restrict__ Bm,
                        int M, int N, int K,
                        float* __restrict__ outF, const float* __restrict__ bias,
                        unsigned short* __restrict__ Qb,
                        unsigned short* __restrict__ Kb,
                        unsigned short* __restrict__ Vtb) {
  constexpr int ASZ = 16384;
  constexpr int BSZ = BN * 128;
  constexpr int SLOT = ASZ + BSZ;
  constexpr int NN = BN / 32;
  __shared__ __align__(16) char lds[2 * SLOT];
  const int tid = threadIdx.x;
  const int wid = tid >> 6;
  const int lane = tid & 63;
  const int llo = lane & 15, lhi = lane >> 4;
  const int row0 = blockIdx.x * 128, col0 = blockIdx.y * BN;
  const int wr = (wid >> 1) * 64, wc = (wid & 1) * (BN / 2);
  const int swl = ((llo >> 2) & 3) << 5;

  f32x4 acc[4][NN];
#pragma unroll
  for (int m = 0; m < 4; ++m)
#pragma unroll
    for (int n = 0; n < NN; ++n) {
      f32x4 z = {0.f, 0.f, 0.f, 0.f};
      acc[m][n] = z;
    }

  auto stage = [&](int kt, char* base) {
#pragma unroll
    for (int c = 0; c < 4; ++c) {
      int off = c * 4096 + tid * 16;
      int r = off >> 7, cb = off & 127;
      int sb = cb ^ (((r >> 2) & 3) << 5);
      load_lds16((const char*)A + ((size_t)(row0 + r) * K + kt) * 2 + sb,
                 base + c * 4096 + wid * 1024);
    }
#pragma unroll
    for (int c = 0; c < BSZ / 4096; ++c) {
      int off = c * 4096 + tid * 16;
      int r = off >> 7, cb = off & 127;
      int sb = cb ^ (((r >> 2) & 3) << 5);
      load_lds16((const char*)Bm + ((size_t)(col0 + r) * K + kt) * 2 + sb,
                 base + ASZ + c * 4096 + wid * 1024);
    }
  };

  stage(0, lds);
  __syncthreads();
  int buf = 0;

  for (int kt = 0; kt < K; kt += 64) {
    char* cur = lds + buf * SLOT;
    if (kt + 64 < K) stage(kt + 64, lds + (buf ^ 1) * SLOT);

    bf16x8 af[4][2], bfr[NN][2];
#pragma unroll
    for (int m = 0; m < 4; ++m)
#pragma unroll
      for (int kk = 0; kk < 2; ++kk)
        af[m][kk] = *reinterpret_cast<const bf16x8*>(
            cur + (wr + m * 16 + llo) * 128 + ((kk * 64 + lhi * 16) ^ swl));
#pragma unroll
    for (int n = 0; n < NN; ++n)
#pragma unroll
      for (int kk = 0; kk < 2; ++kk)
        bfr[n][kk] = *reinterpret_cast<const bf16x8*>(
            cur + ASZ + (wc + n * 16 + llo) * 128 + ((kk * 64 + lhi * 16) ^ swl));
#pragma unroll
    for (int m = 0; m < 4; ++m)
#pragma unroll
      for (int n = 0; n < NN; ++n)
#pragma unroll
        for (int kk = 0; kk < 2; ++kk)
          acc[m][n] = __builtin_amdgcn_mfma_f32_16x16x32_bf16(af[m][kk], bfr[n][kk],
                                                              acc[m][n], 0, 0, 0);
    __syncthreads();
    buf ^= 1;
  }

#pragma unroll
  for (int m = 0; m < 4; ++m)
#pragma unroll
    for (int n = 0; n < NN; ++n) {
      const int grow0 = row0 + wr + m * 16 + lhi * 4;
      const int gcol = col0 + wc + n * 16 + llo;
      if (EPI == 0) {
        int b = grow0 >> 10, t0 = grow0 & 1023;
        int which = gcol >> 10, hd = gcol & 1023;
        int h = hd >> 6, d = hd & 63;
        if (which == 2) {
          unsigned int w0 = cvt_pk(acc[m][n][0], acc[m][n][1]);
          unsigned int w1 = cvt_pk(acc[m][n][2], acc[m][n][3]);
          unsigned long long pk = ((unsigned long long)w1 << 32) | w0;
          *reinterpret_cast<unsigned long long*>(
              Vtb + (((size_t)(b * H_SZ + h)) * D_SZ + d) * T_SZ + t0) = pk;
        } else {
          unsigned short* dst = which ? Kb : Qb;
#pragma unroll
          for (int r = 0; r < 4; ++r)
            dst[(((size_t)(b * H_SZ + h)) * T_SZ + t0 + r) * D_SZ + d] =
                f2b(acc[m][n][r]);
        }
      } else {
#pragma unroll
        for (int r = 0; r < 4; ++r)
          outF[(size_t)(grow0 + r) * N + gcol] = acc[m][n][r] + bias[gcol];
      }
    }
}

// ---------------- flash attention, causal, tile-pair staging (R18) ----------------
__global__ void attn_kernel(const unsigned short* __restrict__ Q,
                            const unsigned short* __restrict__ K,
                            const unsigned short* __restrict__ Vt,
                            unsigned short* __restrict__ O) {
  __shared__ __align__(16) char smem[49152];  // Ks 2x8K | Vs 2x8K | Ps 8x2K
  const int tid = threadIdx.x, wid = tid >> 6, lane = tid & 63;
  const int llo = lane & 15, lhi = lane >> 4;
  const int f = blockIdx.y * 8 + blockIdx.x;
  const int xcd = f & 7, s = f >> 3;
  const int bh = xcd * 8 + (s & 7);             // 8 bh per XCD -> K/V L2-resident
  const int j = s >> 3;
  const int blkx = (j < 4) ? (7 - j) : (j - 4); // complementary pairing, heavy first
  const size_t bhbase = (size_t)bh * (T_SZ * D_SZ);
  char* Ks = smem;              // [2][64][128B] swizzled
  char* Vs = smem + 16384;      // [2][64][128B] swizzled
  char* Ps = smem + 32768 + wid * 2048;

  const int qrow = blkx * 128 + wid * 16 + llo;
  const int myqt = 2 * blkx + (wid >> 2);   // wave's last active 64-key tile (uniform)
  bf16x8 bq[2];
  {
    const unsigned short* qp = Q + bhbase + (size_t)qrow * D_SZ + lhi * 8;
    bq[0] = *reinterpret_cast<const bf16x8*>(qp);
    bq[1] = *reinterpret_cast<const bf16x8*>(qp + 32);
  }

  const int soff = tid * 16;
  const int srow = soff >> 7;          // K: key row / V: d row (0..63)
  const int sinb = soff & 127;
  const int slds = srow * 128 + (sinb ^ ((srow & 7) << 4));

  bf16x8 kreg[2], vreg[2];
#pragma unroll
  for (int c = 0; c < 2; ++c) {
    kreg[c] = *reinterpret_cast<const bf16x8*>(
        K + bhbase + (size_t)(c * 64 + srow) * D_SZ + (sinb >> 1));
    vreg[c] = *reinterpret_cast<const bf16x8*>(
        Vt + bhbase + (size_t)srow * T_SZ + c * 64 + (sinb >> 1));
  }

  f32x4 oacc[4];
#pragma unroll
  for (int dc = 0; dc < 4; ++dc) {
    f32x4 z = {0.f, 0.f, 0.f, 0.f};
    oacc[dc] = z;
  }
  float mrun = -1e30f, lrun = 0.f;
  const float scale = 0.125f;

  for (int pp = 0; pp <= blkx; ++pp) {
    __syncthreads();   // previous pair's compute done: LDS writable
#pragma unroll
    for (int c = 0; c < 2; ++c) {
      *reinterpret_cast<bf16x8*>(Ks + c * 8192 + slds) = kreg[c];
      *reinterpret_cast<bf16x8*>(Vs + c * 8192 + slds) = vreg[c];
    }
    if (pp < blkx) {   // issue next pair's loads; latency hides under compute
      const int kv2 = (pp + 1) * 128;
#pragma unroll
      for (int c = 0; c < 2; ++c) {
        kreg[c] = *reinterpret_cast<const bf16x8*>(
            K + bhbase + (size_t)(kv2 + c * 64 + srow) * D_SZ + (sinb >> 1));
        vreg[c] = *reinterpret_cast<const bf16x8*>(
            Vt + bhbase + (size_t)srow * T_SZ + kv2 + c * 64 + (sinb >> 1));
      }
    }
    __syncthreads();   // pair visible to all waves

#pragma unroll
    for (int h = 0; h < 2; ++h) {
      const int it = 2 * pp + h;
      if (it <= myqt) {   // wave-uniform causal skip
        const char* Ksh = Ks + h * 8192;
        const char* Vsh = Vs + h * 8192;
        const int kv = it * 64;

        f32x4 sacc[4];
#pragma unroll
        for (int c = 0; c < 4; ++c) { f32x4 z = {0.f, 0.f, 0.f, 0.f}; sacc[c] = z; }
        __builtin_amdgcn_s_setprio(1);
#pragma unroll
        for (int seg = 0; seg < 2; ++seg)
#pragma unroll
          for (int c = 0; c < 4; ++c) {
            int key = c * 16 + llo;
            bf16x8 ak = *reinterpret_cast<const bf16x8*>(
                Ksh + key * 128 + ((seg * 64 + lhi * 16) ^ ((key & 7) << 4)));
            sacc[c] = __builtin_amdgcn_mfma_f32_16x16x32_bf16(ak, bq[seg], sacc[c], 0, 0, 0);
          }
        __builtin_amdgcn_s_setprio(0);

        const bool diag = (it == myqt);
        float p[4][4];
        float pm = -1e30f;
#pragma unroll
        for (int c = 0; c < 4; ++c)
#pragma unroll
          for (int r = 0; r < 4; ++r) {
            float s2 = sacc[c][r] * scale;
            if (diag && (kv + c * 16 + lhi * 4 + r > qrow)) s2 = -1e30f;
            p[c][r] = s2;
            pm = fmaxf(pm, s2);
          }
        pm = fmaxf(pm, __shfl_xor(pm, 16, 64));
        pm = fmaxf(pm, __shfl_xor(pm, 32, 64));
        if (!__all(pm - mrun <= 8.0f)) {   // T13 defer-max
          float mnew = fmaxf(mrun, pm);
          float alpha = __expf(mrun - mnew);
          mrun = mnew;
          lrun *= alpha;
#pragma unroll
          for (int dc = 0; dc < 4; ++dc)
#pragma unroll
            for (int r = 0; r < 4; ++r) oacc[dc][r] *= alpha;
        }

        float ps = 0.f;
#pragma unroll
        for (int c = 0; c < 4; ++c) {
#pragma unroll
          for (int r = 0; r < 4; ++r) {
            p[c][r] = __expf(p[c][r] - mrun);
            ps += p[c][r];
          }
          unsigned int w0 = cvt_pk(p[c][0], p[c][1]);
          unsigned int w1 = cvt_pk(p[c][2], p[c][3]);
          unsigned long long packed = ((unsigned long long)w1 << 32) | w0;
          *reinterpret_cast<bf16x4*>(
              Ps + llo * 128 + ((c * 32 + lhi * 8) ^ ((llo & 7) << 4))) =
              __builtin_bit_cast(bf16x4, packed);
        }
        // Hard fence: Ps ds_writes retired before PV ds_reads (rule-18 pattern).
        asm volatile("s_waitcnt lgkmcnt(0)" ::: "memory");
        __builtin_amdgcn_sched_barrier(0);

        ps += __shfl_xor(ps, 16, 64);
        ps += __shfl_xor(ps, 32, 64);
        lrun += ps;

        __builtin_amdgcn_s_setprio(1);
#pragma unroll
        for (int seg = 0; seg < 2; ++seg) {
          bf16x8 bp = *reinterpret_cast<const bf16x8*>(
              Ps + llo * 128 + ((seg * 64 + lhi * 16) ^ ((llo & 7) << 4)));
#pragma unroll
          for (int dc = 0; dc < 4; ++dc) {
            int d = dc * 16 + llo;
            bf16x8 av = *reinterpret_cast<const bf16x8*>(
                Vsh + d * 128 + ((seg * 64 + lhi * 16) ^ ((d & 7) << 4)));
            oacc[dc] = __builtin_amdgcn_mfma_f32_16x16x32_bf16(av, bp, oacc[dc], 0, 0, 0);
          }
        }
        __builtin_amdgcn_s_setprio(0);
      }
    }
  }

  const int b = bh >> 4, h = bh & 15;
  float inv = 1.f / lrun;
#pragma unroll
  for (int dc = 0; dc < 4; ++dc) {
    unsigned int w0 = cvt_pk(oacc[dc][0] * inv, oacc[dc][1] * inv);
    unsigned int w1 = cvt_pk(oacc[dc][2] * inv, oacc[dc][3] * inv);
    unsigned int* op = reinterpret_cast<unsigned int*>(
        O + ((size_t)b * T_SZ + qrow) * E_SZ + h * D_SZ + dc * 16 + lhi * 4);
    op[0] = w0;
    op[1] = w1;
  }
}

// ---------------- launch ----------------
extern "C" void kernel_launch(void* const* d_in, const int* in_sizes, int n_in,
                              void* d_out, int out_size, void* d_ws, size_t ws_size,
                              hipStream_t stream) {
  const float* x  = (const float*)d_in[0];
  const float* Wq = (const float*)d_in[1];
  const float* Wk = (const float*)d_in[2];
  const float* Wv = (const float*)d_in[3];
  const float* Wp = (const float*)d_in[4];
  const float* bp = (const float*)d_in[5];
  float* out = (float*)d_out;

  char* ws = (char*)d_ws;
  unsigned short* xb   = (unsigned short*)(ws);                    // 8 MB [4096,1024]
  unsigned short* wqkv = (unsigned short*)(ws + (8u << 20));       // 6 MB [3072,1024]
  unsigned short* wp   = (unsigned short*)(ws + (14u << 20));      // 2 MB [1024,1024]
  unsigned short* Qb   = (unsigned short*)(ws + (16u << 20));      // 8 MB [B,H,T,D]
  unsigned short* Kb   = (unsigned short*)(ws + (24u << 20));      // 8 MB [B,H,T,D]
  unsigned short* Vtb  = (unsigned short*)(ws + (32u << 20));      // 8 MB [B,H,D,T]
  unsigned short* Ob   = (unsigned short*)(ws + (40u << 20));      // 8 MB [B,T,E]

  cast_all<<<8192, 256, 0, stream>>>(x, Wq, Wk, Wv, Wp, xb, wqkv, wp);

  gemm_bt<0, 64><<<dim3(32, 48), 256, 0, stream>>>(xb, wqkv, 4096, 3072, 1024,
                                                   nullptr, nullptr, Qb, Kb, Vtb);
  attn_kernel<<<dim3(8, 64), 512, 0, stream>>>(Qb, Kb, Vtb, Ob);
  gemm_bt<1, 64><<<dim3(32, 16), 256, 0, stream>>>(Ob, wp, 4096, 1024, 1024,
                                                   out, bp, nullptr, nullptr, nullptr);
}

// Round 20
// 81.320 us; speedup vs baseline: 1.0271x; 1.0271x over previous
//
#include <hip/hip_runtime.h>

// MHA: B=4 T=1024 E=1024 H=16 D=64, causal, f32 in/out, bf16 internal compute.
// cast -> GEMM1 (Q/K plain [B,H,T,D], V direct-transposed [B,H,D,T]) -> flash attn
// -> GEMM2 (+bias)
// R20: restore R18 (best measured, 81.5us). R19's GEMM1 BN=64 regressed (per-step
//      stall unamortized + A re-read pressure). GEMM1 is ~LDS-read-port-bound at this
//      structure; the 8-phase escape failed twice (R16) and stays closed.

#define T_SZ 1024
#define E_SZ 1024
#define H_SZ 16
#define D_SZ 64

typedef __attribute__((ext_vector_type(8))) short bf16x8;
typedef __attribute__((ext_vector_type(4))) short bf16x4;
typedef __attribute__((ext_vector_type(4))) float f32x4;

static __device__ __forceinline__ unsigned short f2b(float f) {
  unsigned int u = __builtin_bit_cast(unsigned int, f);
  u += 0x7fffu + ((u >> 16) & 1u);   // RNE
  return (unsigned short)(u >> 16);
}

static __device__ __forceinline__ unsigned int cvt_pk(float lo, float hi) {
  unsigned int r;
  asm("v_cvt_pk_bf16_f32 %0, %1, %2" : "=v"(r) : "v"(lo), "v"(hi));
  return r;
}

static __device__ __forceinline__ void load_lds16(const void* g, void* l) {
  __builtin_amdgcn_global_load_lds(
      (const __attribute__((address_space(1))) void*)g,
      (__attribute__((address_space(3))) void*)l, 16, 0, 0);
}

// ---------------- fused cast f32 -> bf16 ----------------
__global__ void cast_all(const float* __restrict__ x, const float* __restrict__ wq,
                         const float* __restrict__ wk, const float* __restrict__ wv,
                         const float* __restrict__ wp,
                         unsigned short* __restrict__ xb,
                         unsigned short* __restrict__ wqkvb,
                         unsigned short* __restrict__ wpb) {
  int b = blockIdx.x;
  const float4* src;
  ushort4* dst;
  int i;
  if (b < 4096) {
    src = (const float4*)x; dst = (ushort4*)xb; i = b * 256 + threadIdx.x;
  } else {
    int a = (b - 4096) >> 10;
    i = ((b - 4096) & 1023) * 256 + threadIdx.x;
    src = (const float4*)(a == 0 ? wq : a == 1 ? wk : a == 2 ? wv : wp);
    dst = (ushort4*)(a == 3 ? wpb : wqkvb + (size_t)a * 1048576);
  }
  float4 v = src[i];
  ushort4 o;
  o.x = f2b(v.x); o.y = f2b(v.y); o.z = f2b(v.z); o.w = f2b(v.w);
  dst[i] = o;
}

// ---------------- GEMM C[M,N] = A[M,K] * B[N,K]^T (R15-proven) ----------------
template <int EPI, int BN>
__global__ void gemm_bt(const unsigned short* __restrict__ A,
                        const unsigned short* __restrict__ Bm,
                        int M, int N, int K,
                        float* __restrict__ outF, const float* __restrict__ bias,
                        unsigned short* __restrict__ Qb,
                        unsigned short* __restrict__ Kb,
                        unsigned short* __restrict__ Vtb) {
  constexpr int ASZ = 16384;
  constexpr int BSZ = BN * 128;
  constexpr int SLOT = ASZ + BSZ;
  constexpr int NN = BN / 32;
  __shared__ __align__(16) char lds[2 * SLOT];
  const int tid = threadIdx.x;
  const int wid = tid >> 6;
  const int lane = tid & 63;
  const int llo = lane & 15, lhi = lane >> 4;
  const int row0 = blockIdx.x * 128, col0 = blockIdx.y * BN;
  const int wr = (wid >> 1) * 64, wc = (wid & 1) * (BN / 2);
  const int swl = ((llo >> 2) & 3) << 5;

  f32x4 acc[4][NN];
#pragma unroll
  for (int m = 0; m < 4; ++m)
#pragma unroll
    for (int n = 0; n < NN; ++n) {
      f32x4 z = {0.f, 0.f, 0.f, 0.f};
      acc[m][n] = z;
    }

  auto stage = [&](int kt, char* base) {
#pragma unroll
    for (int c = 0; c < 4; ++c) {
      int off = c * 4096 + tid * 16;
      int r = off >> 7, cb = off & 127;
      int sb = cb ^ (((r >> 2) & 3) << 5);
      load_lds16((const char*)A + ((size_t)(row0 + r) * K + kt) * 2 + sb,
                 base + c * 4096 + wid * 1024);
    }
#pragma unroll
    for (int c = 0; c < BSZ / 4096; ++c) {
      int off = c * 4096 + tid * 16;
      int r = off >> 7, cb = off & 127;
      int sb = cb ^ (((r >> 2) & 3) << 5);
      load_lds16((const char*)Bm + ((size_t)(col0 + r) * K + kt) * 2 + sb,
                 base + ASZ + c * 4096 + wid * 1024);
    }
  };

  stage(0, lds);
  __syncthreads();
  int buf = 0;

  for (int kt = 0; kt < K; kt += 64) {
    char* cur = lds + buf * SLOT;
    if (kt + 64 < K) stage(kt + 64, lds + (buf ^ 1) * SLOT);

    bf16x8 af[4][2], bfr[NN][2];
#pragma unroll
    for (int m = 0; m < 4; ++m)
#pragma unroll
      for (int kk = 0; kk < 2; ++kk)
        af[m][kk] = *reinterpret_cast<const bf16x8*>(
            cur + (wr + m * 16 + llo) * 128 + ((kk * 64 + lhi * 16) ^ swl));
#pragma unroll
    for (int n = 0; n < NN; ++n)
#pragma unroll
      for (int kk = 0; kk < 2; ++kk)
        bfr[n][kk] = *reinterpret_cast<const bf16x8*>(
            cur + ASZ + (wc + n * 16 + llo) * 128 + ((kk * 64 + lhi * 16) ^ swl));
#pragma unroll
    for (int m = 0; m < 4; ++m)
#pragma unroll
      for (int n = 0; n < NN; ++n)
#pragma unroll
        for (int kk = 0; kk < 2; ++kk)
          acc[m][n] = __builtin_amdgcn_mfma_f32_16x16x32_bf16(af[m][kk], bfr[n][kk],
                                                              acc[m][n], 0, 0, 0);
    __syncthreads();
    buf ^= 1;
  }

#pragma unroll
  for (int m = 0; m < 4; ++m)
#pragma unroll
    for (int n = 0; n < NN; ++n) {
      const int grow0 = row0 + wr + m * 16 + lhi * 4;
      const int gcol = col0 + wc + n * 16 + llo;
      if (EPI == 0) {
        int b = grow0 >> 10, t0 = grow0 & 1023;
        int which = gcol >> 10, hd = gcol & 1023;
        int h = hd >> 6, d = hd & 63;
        if (which == 2) {
          unsigned int w0 = cvt_pk(acc[m][n][0], acc[m][n][1]);
          unsigned int w1 = cvt_pk(acc[m][n][2], acc[m][n][3]);
          unsigned long long pk = ((unsigned long long)w1 << 32) | w0;
          *reinterpret_cast<unsigned long long*>(
              Vtb + (((size_t)(b * H_SZ + h)) * D_SZ + d) * T_SZ + t0) = pk;
        } else {
          unsigned short* dst = which ? Kb : Qb;
#pragma unroll
          for (int r = 0; r < 4; ++r)
            dst[(((size_t)(b * H_SZ + h)) * T_SZ + t0 + r) * D_SZ + d] =
                f2b(acc[m][n][r]);
        }
      } else {
#pragma unroll
        for (int r = 0; r < 4; ++r)
          outF[(size_t)(grow0 + r) * N + gcol] = acc[m][n][r] + bias[gcol];
      }
    }
}

// ---------------- flash attention, causal, tile-pair staging (R18) ----------------
__global__ void attn_kernel(const unsigned short* __restrict__ Q,
                            const unsigned short* __restrict__ K,
                            const unsigned short* __restrict__ Vt,
                            unsigned short* __restrict__ O) {
  __shared__ __align__(16) char smem[49152];  // Ks 2x8K | Vs 2x8K | Ps 8x2K
  const int tid = threadIdx.x, wid = tid >> 6, lane = tid & 63;
  const int llo = lane & 15, lhi = lane >> 4;
  const int f = blockIdx.y * 8 + blockIdx.x;
  const int xcd = f & 7, s = f >> 3;
  const int bh = xcd * 8 + (s & 7);             // 8 bh per XCD -> K/V L2-resident
  const int j = s >> 3;
  const int blkx = (j < 4) ? (7 - j) : (j - 4); // complementary pairing, heavy first
  const size_t bhbase = (size_t)bh * (T_SZ * D_SZ);
  char* Ks = smem;              // [2][64][128B] swizzled
  char* Vs = smem + 16384;      // [2][64][128B] swizzled
  char* Ps = smem + 32768 + wid * 2048;

  const int qrow = blkx * 128 + wid * 16 + llo;
  const int myqt = 2 * blkx + (wid >> 2);   // wave's last active 64-key tile (uniform)
  bf16x8 bq[2];
  {
    const unsigned short* qp = Q + bhbase + (size_t)qrow * D_SZ + lhi * 8;
    bq[0] = *reinterpret_cast<const bf16x8*>(qp);
    bq[1] = *reinterpret_cast<const bf16x8*>(qp + 32);
  }

  const int soff = tid * 16;
  const int srow = soff >> 7;          // K: key row / V: d row (0..63)
  const int sinb = soff & 127;
  const int slds = srow * 128 + (sinb ^ ((srow & 7) << 4));

  bf16x8 kreg[2], vreg[2];
#pragma unroll
  for (int c = 0; c < 2; ++c) {
    kreg[c] = *reinterpret_cast<const bf16x8*>(
        K + bhbase + (size_t)(c * 64 + srow) * D_SZ + (sinb >> 1));
    vreg[c] = *reinterpret_cast<const bf16x8*>(
        Vt + bhbase + (size_t)srow * T_SZ + c * 64 + (sinb >> 1));
  }

  f32x4 oacc[4];
#pragma unroll
  for (int dc = 0; dc < 4; ++dc) {
    f32x4 z = {0.f, 0.f, 0.f, 0.f};
    oacc[dc] = z;
  }
  float mrun = -1e30f, lrun = 0.f;
  const float scale = 0.125f;

  for (int pp = 0; pp <= blkx; ++pp) {
    __syncthreads();   // previous pair's compute done: LDS writable
#pragma unroll
    for (int c = 0; c < 2; ++c) {
      *reinterpret_cast<bf16x8*>(Ks + c * 8192 + slds) = kreg[c];
      *reinterpret_cast<bf16x8*>(Vs + c * 8192 + slds) = vreg[c];
    }
    if (pp < blkx) {   // issue next pair's loads; latency hides under compute
      const int kv2 = (pp + 1) * 128;
#pragma unroll
      for (int c = 0; c < 2; ++c) {
        kreg[c] = *reinterpret_cast<const bf16x8*>(
            K + bhbase + (size_t)(kv2 + c * 64 + srow) * D_SZ + (sinb >> 1));
        vreg[c] = *reinterpret_cast<const bf16x8*>(
            Vt + bhbase + (size_t)srow * T_SZ + kv2 + c * 64 + (sinb >> 1));
      }
    }
    __syncthreads();   // pair visible to all waves

#pragma unroll
    for (int h = 0; h < 2; ++h) {
      const int it = 2 * pp + h;
      if (it <= myqt) {   // wave-uniform causal skip
        const char* Ksh = Ks + h * 8192;
        const char* Vsh = Vs + h * 8192;
        const int kv = it * 64;

        f32x4 sacc[4];
#pragma unroll
        for (int c = 0; c < 4; ++c) { f32x4 z = {0.f, 0.f, 0.f, 0.f}; sacc[c] = z; }
        __builtin_amdgcn_s_setprio(1);
#pragma unroll
        for (int seg = 0; seg < 2; ++seg)
#pragma unroll
          for (int c = 0; c < 4; ++c) {
            int key = c * 16 + llo;
            bf16x8 ak = *reinterpret_cast<const bf16x8*>(
                Ksh + key * 128 + ((seg * 64 + lhi * 16) ^ ((key & 7) << 4)));
            sacc[c] = __builtin_amdgcn_mfma_f32_16x16x32_bf16(ak, bq[seg], sacc[c], 0, 0, 0);
          }
        __builtin_amdgcn_s_setprio(0);

        const bool diag = (it == myqt);
        float p[4][4];
        float pm = -1e30f;
#pragma unroll
        for (int c = 0; c < 4; ++c)
#pragma unroll
          for (int r = 0; r < 4; ++r) {
            float s2 = sacc[c][r] * scale;
            if (diag && (kv + c * 16 + lhi * 4 + r > qrow)) s2 = -1e30f;
            p[c][r] = s2;
            pm = fmaxf(pm, s2);
          }
        pm = fmaxf(pm, __shfl_xor(pm, 16, 64));
        pm = fmaxf(pm, __shfl_xor(pm, 32, 64));
        if (!__all(pm - mrun <= 8.0f)) {   // T13 defer-max
          float mnew = fmaxf(mrun, pm);
          float alpha = __expf(mrun - mnew);
          mrun = mnew;
          lrun *= alpha;
#pragma unroll
          for (int dc = 0; dc < 4; ++dc)
#pragma unroll
            for (int r = 0; r < 4; ++r) oacc[dc][r] *= alpha;
        }

        float ps = 0.f;
#pragma unroll
        for (int c = 0; c < 4; ++c) {
#pragma unroll
          for (int r = 0; r < 4; ++r) {
            p[c][r] = __expf(p[c][r] - mrun);
            ps += p[c][r];
          }
          unsigned int w0 = cvt_pk(p[c][0], p[c][1]);
          unsigned int w1 = cvt_pk(p[c][2], p[c][3]);
          unsigned long long packed = ((unsigned long long)w1 << 32) | w0;
          *reinterpret_cast<bf16x4*>(
              Ps + llo * 128 + ((c * 32 + lhi * 8) ^ ((llo & 7) << 4))) =
              __builtin_bit_cast(bf16x4, packed);
        }
        // Hard fence: Ps ds_writes retired before PV ds_reads (rule-18 pattern).
        asm volatile("s_waitcnt lgkmcnt(0)" ::: "memory");
        __builtin_amdgcn_sched_barrier(0);

        ps += __shfl_xor(ps, 16, 64);
        ps += __shfl_xor(ps, 32, 64);
        lrun += ps;

        __builtin_amdgcn_s_setprio(1);
#pragma unroll
        for (int seg = 0; seg < 2; ++seg) {
          bf16x8 bp = *reinterpret_cast<const bf16x8*>(
              Ps + llo * 128 + ((seg * 64 + lhi * 16) ^ ((llo & 7) << 4)));
#pragma unroll
          for (int dc = 0; dc < 4; ++dc) {
            int d = dc * 16 + llo;
            bf16x8 av = *reinterpret_cast<const bf16x8*>(
                Vsh + d * 128 + ((seg * 64 + lhi * 16) ^ ((d & 7) << 4)));
            oacc[dc] = __builtin_amdgcn_mfma_f32_16x16x32_bf16(av, bp, oacc[dc], 0, 0, 0);
          }
        }
        __builtin_amdgcn_s_setprio(0);
      }
    }
  }

  const int b = bh >> 4, h = bh & 15;
  float inv = 1.f / lrun;
#pragma unroll
  for (int dc = 0; dc < 4; ++dc) {
    unsigned int w0 = cvt_pk(oacc[dc][0] * inv, oacc[dc][1] * inv);
    unsigned int w1 = cvt_pk(oacc[dc][2] * inv, oacc[dc][3] * inv);
    unsigned int* op = reinterpret_cast<unsigned int*>(
        O + ((size_t)b * T_SZ + qrow) * E_SZ + h * D_SZ + dc * 16 + lhi * 4);
    op[0] = w0;
    op[1] = w1;
  }
}

// ---------------- launch ----------------
extern "C" void kernel_launch(void* const* d_in, const int* in_sizes, int n_in,
                              void* d_out, int out_size, void* d_ws, size_t ws_size,
                              hipStream_t stream) {
  const float* x  = (const float*)d_in[0];
  const float* Wq = (const float*)d_in[1];
  const float* Wk = (const float*)d_in[2];
  const float* Wv = (const float*)d_in[3];
  const float* Wp = (const float*)d_in[4];
  const float* bp = (const float*)d_in[5];
  float* out = (float*)d_out;

  char* ws = (char*)d_ws;
  unsigned short* xb   = (unsigned short*)(ws);                    // 8 MB [4096,1024]
  unsigned short* wqkv = (unsigned short*)(ws + (8u << 20));       // 6 MB [3072,1024]
  unsigned short* wp   = (unsigned short*)(ws + (14u << 20));      // 2 MB [1024,1024]
  unsigned short* Qb   = (unsigned short*)(ws + (16u << 20));      // 8 MB [B,H,T,D]
  unsigned short* Kb   = (unsigned short*)(ws + (24u << 20));      // 8 MB [B,H,T,D]
  unsigned short* Vtb  = (unsigned short*)(ws + (32u << 20));      // 8 MB [B,H,D,T]
  unsigned short* Ob   = (unsigned short*)(ws + (40u << 20));      // 8 MB [B,T,E]

  cast_all<<<8192, 256, 0, stream>>>(x, Wq, Wk, Wv, Wp, xb, wqkv, wp);

  gemm_bt<0, 128><<<dim3(32, 24), 256, 0, stream>>>(xb, wqkv, 4096, 3072, 1024,
                                                    nullptr, nullptr, Qb, Kb, Vtb);
  attn_kernel<<<dim3(8, 64), 512, 0, stream>>>(Qb, Kb, Vtb, Ob);
  gemm_bt<1, 64><<<dim3(32, 16), 256, 0, stream>>>(Ob, wp, 4096, 1024, 1024,
                                                   out, bp, nullptr, nullptr, nullptr);
}